// Round 1
// baseline (68.392 us; speedup 1.0000x reference)
//
#include <hip/hip_runtime.h>

#define EPSLN 1e-5f
#define KMINC 9

__device__ __forceinline__ float wred64(float v){
  #pragma unroll
  for (int m=1;m<64;m<<=1) v += __shfl_xor(v,m,64);
  return v;
}
__device__ __forceinline__ float wred32(float v){
  #pragma unroll
  for (int m=1;m<32;m<<=1) v += __shfl_xor(v,m,64);
  return v;
}

// ---------------- Kernel A: msa LN -> 1-query attention -> node ----------------
// grid = B*L (512), block = 64
__global__ __launch_bounds__(64) void k_node(
    const float* __restrict__ msa, const float* __restrict__ seq1hot,
    const float* __restrict__ g_msa, const float* __restrict__ b_msa,
    const float* __restrict__ Wq, const float* __restrict__ bq,
    const float* __restrict__ Wk, const float* __restrict__ bk,
    const float* __restrict__ Wx, const float* __restrict__ bx,
    const float* __restrict__ g_node, const float* __restrict__ b_node,
    float* __restrict__ node)
{
  const int bid = blockIdx.x;          // b*256 + l
  const int b = bid >> 8, l = bid & 255;
  const int t = threadIdx.x;
  __shared__ float mn[32][64];
  __shared__ float sh[64];
  __shared__ float scS[32];
  const float gm = g_msa[t], bm = b_msa[t];
  for (int nn=0; nn<32; nn++){
    float x = msa[(size_t)(((b*32+nn)<<8)+l)*64 + t];
    float s = wred64(x), s2 = wred64(x*x);
    float mu = s*(1.f/64.f);
    float var = s2*(1.f/64.f) - mu*mu;
    mn[nn][t] = (x-mu)*rsqrtf(var+EPSLN)*gm + bm;
  }
  __syncthreads();
  // q[e=t] from n=0 row
  float q = bq[t];
  for (int d=0; d<64; d++) q += mn[0][d]*Wq[d*64+t];
  q *= 0.125f;                          // 1/sqrt(64)
  sh[t] = q;
  __syncthreads();
  // qk[d=t] = sum_e Wk[d,e]*q[e];  score[n] = sum_d mn[n][d]*qk[d] + sum_e q[e]*bk[e]
  float qk = 0.f;
  for (int e=0; e<64; e++) qk += Wk[t*64+e]*sh[e];
  float qb = wred64(q*bk[t]);
  for (int nn=0; nn<32; nn++){
    float p = wred64(mn[nn][t]*qk);
    if (t==0) scS[nn] = p + qb;
  }
  __syncthreads();
  float mx = -1e30f;
  for (int nn=0; nn<32; nn++) mx = fmaxf(mx, scS[nn]);
  float ssum = 0.f, mw = 0.f;
  for (int nn=0; nn<32; nn++){
    float e = expf(scS[nn]-mx);
    ssum += e;
    mw += e*mn[nn][t];
  }
  mw /= ssum;                           // msa_w[d=t]
  __syncthreads();
  sh[t] = mw;
  __syncthreads();
  if (t<32){
    float acc = bx[t];
    for (int k=0;k<64;k++) acc += sh[k]*Wx[k*32+t];
    const float* s1 = &seq1hot[bid*21];
    for (int k=0;k<21;k++) acc += s1[k]*Wx[(64+k)*32+t];
    float s = wred32(acc), s2 = wred32(acc*acc);
    float mu = s*(1.f/32.f), var = s2*(1.f/32.f)-mu*mu;
    node[bid*32+t] = (acc-mu)*rsqrtf(var+EPSLN)*g_node[t] + b_node[t];
  }
}

// ---------------- Kernel B: D, exact stable top-k rank, mask compaction ----------------
// grid = B*L (512), block = 256 (thread = j)
__global__ __launch_bounds__(256) void k_mask(
    const float* __restrict__ xyz, const int* __restrict__ idxp,
    const int* __restrict__ topk,
    int* __restrict__ cnt, int* __restrict__ jlist)
{
  const int bid = blockIdx.x;
  const int b = bid >> 8, i = bid & 255;
  const int j = threadIdx.x;
  __shared__ float Dv[256];
  __shared__ int wsum[4];
  const float cax = xyz[(bid*3+1)*3+0];
  const float cay = xyz[(bid*3+1)*3+1];
  const float caz = xyz[(bid*3+1)*3+2];
  const int jb = (b<<8)+j;
  float dx = xyz[(jb*3+1)*3+0]-cax;
  float dy = xyz[(jb*3+1)*3+1]-cay;
  float dz = xyz[(jb*3+1)*3+2]-caz;
  float D = sqrtf(dx*dx+dy*dy+dz*dz) + (i==j ? 999.9f : 0.f);
  Dv[j] = D;
  __syncthreads();
  int rank = 0;
  for (int j2=0;j2<256;j2++){
    float v = Dv[j2];
    rank += (v < D || (v == D && j2 < j)) ? 1 : 0;
  }
  int K = topk[0];                       // robust to int32/int64(LE)/float storage
  if (K<=0 || K>256){
    float f = ((const float*)topk)[0];
    K = (f>=1.f && f<=256.f) ? (int)f : 64;
  }
  const int sep = abs(idxp[jb] - idxp[bid]);
  const bool m = (rank < K) || (i!=j && sep < KMINC);
  unsigned long long bal = __ballot(m);
  const int lane = j & 63, w = j >> 6;
  const int pre = __popcll(bal & ((1ull<<lane)-1ull));
  if (lane==0) wsum[w] = __popcll(bal);
  __syncthreads();
  int off = 0;
  for (int w2=0;w2<w;w2++) off += wsum[w2];
  if (m) jlist[bid*256 + off + pre] = j;
  if (j==0) cnt[bid] = wsum[0]+wsum[1]+wsum[2]+wsum[3];
}

// ---------------- Kernel C: gathered pair pipeline + masked aggregation ----------------
// grid = B*L (512), block = 256 = 8 groups of 32 lanes; each group does 4 j per iter
__global__ __launch_bounds__(256) void k_main(
    const float* __restrict__ pair, const float* __restrict__ xyz,
    const float* __restrict__ g_pair, const float* __restrict__ b_pair,
    const float* __restrict__ We, const float* __restrict__ be,
    const float* __restrict__ g_edge, const float* __restrict__ b_edge,
    const float* __restrict__ Wa, const float* __restrict__ ba,
    const float* __restrict__ W0, const float* __restrict__ b0,
    const float* __restrict__ Wc1, const float* __restrict__ Wc2,
    const float* __restrict__ node, const int* __restrict__ cnt,
    const int* __restrict__ jlist, float* __restrict__ out)
{
  const int bid = blockIdx.x;
  const int b = bid >> 8;
  const int tid = threadIdx.x;
  const int r = tid >> 5, t = tid & 31;

  __shared__ float WeS[128*32];
  __shared__ float WaS[33*32];
  __shared__ float W0S[96*16];
  __shared__ float WcS[32*12];
  __shared__ float ndI[32];
  __shared__ float pnS[32*128];
  __shared__ float edS[32*32];
  __shared__ float aS[32*32];
  __shared__ float ndS[32*32];
  __shared__ float cS[32*12];
  __shared__ float redS[8][16];
  __shared__ float redO[8][9];
  __shared__ float offF[9];

  for (int k=tid;k<128*32;k+=256) WeS[k]=We[k];
  for (int k=tid;k<33*32;k+=256) WaS[k]=Wa[k];
  for (int k=tid;k<96*16;k+=256) W0S[k]=W0[k];
  for (int k=tid;k<32*12;k+=256){
    int row=k/12, col=k-row*12;
    WcS[k] = (col<3) ? Wc1[row*3+col] : Wc2[row*9+(col-3)];
  }
  if (tid<32) ndI[tid]=node[bid*32+tid];
  __syncthreads();

  const float cax = xyz[(bid*3+1)*3+0];
  const float cay = xyz[(bid*3+1)*3+1];
  const float caz = xyz[(bid*3+1)*3+2];
  const int n = cnt[bid];

  // m0 base: b0 + node_i @ W0[32:64]
  float m0b = 0.f;
  if (t<16){
    m0b = b0[t];
    for (int k=0;k<32;k++) m0b += ndI[k]*W0S[(32+k)*16+t];
  }
  const float gp0=g_pair[t], gp1=g_pair[t+32], gp2=g_pair[t+64], gp3=g_pair[t+96];
  const float bp0=b_pair[t], bp1=b_pair[t+32], bp2=b_pair[t+64], bp3=b_pair[t+96];
  const float beT=be[t], geT=g_edge[t], beeT=b_edge[t], baT=ba[t];

  float stA = 0.f;   // t<16: state partial
  float ofA = 0.f;   // t<9 : offset partial

  for (int base=0; base<n; base+=32){
    int jjs[4]; bool vals[4];
    float jxs[4], jys[4], jzs[4], dsts[4];
    #pragma unroll
    for (int jc=0;jc<4;jc++){
      const int slot = base + r*4 + jc;
      vals[jc] = slot < n;
      jjs[jc] = vals[jc] ? jlist[bid*256+slot] : 0;
    }
    // pair-row LN (128) + stage pn + stage node_j
    #pragma unroll
    for (int jc=0;jc<4;jc++){
      const float* prow = &pair[((long)bid*256 + jjs[jc])*128];
      float p0=prow[t], p1=prow[t+32], p2=prow[t+64], p3=prow[t+96];
      float s = wred32(p0+p1+p2+p3);
      float s2 = wred32(p0*p0+p1*p1+p2*p2+p3*p3);
      float mu = s*(1.f/128.f);
      float var = s2*(1.f/128.f)-mu*mu;
      float rs = rsqrtf(var+EPSLN);
      float* pd = &pnS[(r*4+jc)*128];
      pd[t]    =(p0-mu)*rs*gp0+bp0;
      pd[t+32] =(p1-mu)*rs*gp1+bp1;
      pd[t+64] =(p2-mu)*rs*gp2+bp2;
      pd[t+96] =(p3-mu)*rs*gp3+bp3;
      const int jb=(b<<8)+jjs[jc];
      ndS[(r*4+jc)*32+t] = node[jb*32+t];
      jxs[jc]=xyz[(jb*3+1)*3+0]-cax;
      jys[jc]=xyz[(jb*3+1)*3+1]-cay;
      jzs[jc]=xyz[(jb*3+1)*3+2]-caz;
      dsts[jc]=sqrtf(jxs[jc]*jxs[jc]+jys[jc]*jys[jc]+jzs[jc]*jzs[jc]);
    }
    // edge GEMV (128 -> 32), 4-j weight reuse
    float ea[4]; ea[0]=ea[1]=ea[2]=ea[3]=beT;
    for (int k=0;k<128;k+=4){
      const float w0=WeS[k*32+t], w1=WeS[(k+1)*32+t], w2=WeS[(k+2)*32+t], w3=WeS[(k+3)*32+t];
      #pragma unroll
      for (int jc=0;jc<4;jc++){
        const float4 pv = *(const float4*)&pnS[(r*4+jc)*128+k];
        ea[jc] += pv.x*w0 + pv.y*w1 + pv.z*w2 + pv.w*w3;
      }
    }
    // edge LN (32)
    #pragma unroll
    for (int jc=0;jc<4;jc++){
      float acc=ea[jc];
      float s=wred32(acc), s2=wred32(acc*acc);
      float mu=s*(1.f/32.f), var=s2*(1.f/32.f)-mu*mu;
      edS[(r*4+jc)*32+t] = (acc-mu)*rsqrtf(var+EPSLN)*geT+beeT;
    }
    // a = relu([edge, dist] @ Wa + ba)
    float av[4];
    #pragma unroll
    for (int jc=0;jc<4;jc++) av[jc]=baT+dsts[jc]*WaS[32*32+t];
    for (int k=0;k<32;k+=4){
      const float w0=WaS[k*32+t], w1=WaS[(k+1)*32+t], w2=WaS[(k+2)*32+t], w3=WaS[(k+3)*32+t];
      #pragma unroll
      for (int jc=0;jc<4;jc++){
        const float4 ev = *(const float4*)&edS[(r*4+jc)*32+k];
        av[jc] += ev.x*w0 + ev.y*w1 + ev.z*w2 + ev.w*w3;
      }
    }
    #pragma unroll
    for (int jc=0;jc<4;jc++) aS[(r*4+jc)*32+t]=fmaxf(av[jc],0.f);
    // m0 = relu([a, node_i, node_j] @ W0 + b0)   (t<16)
    if (t<16){
      float m0a[4]={m0b,m0b,m0b,m0b};
      for (int k=0;k<32;k+=4){
        const float wa0=W0S[k*16+t], wa1=W0S[(k+1)*16+t], wa2=W0S[(k+2)*16+t], wa3=W0S[(k+3)*16+t];
        const float wn0=W0S[(64+k)*16+t], wn1=W0S[(64+k+1)*16+t], wn2=W0S[(64+k+2)*16+t], wn3=W0S[(64+k+3)*16+t];
        #pragma unroll
        for (int jc=0;jc<4;jc++){
          const float4 avv = *(const float4*)&aS[(r*4+jc)*32+k];
          const float4 nv  = *(const float4*)&ndS[(r*4+jc)*32+k];
          m0a[jc] += avv.x*wa0+avv.y*wa1+avv.z*wa2+avv.w*wa3
                   + nv.x*wn0 + nv.y*wn1 + nv.z*wn2 + nv.w*wn3;
        }
      }
      #pragma unroll
      for (int jc=0;jc<4;jc++) if (vals[jc]) stA += fmaxf(m0a[jc],0.f);
    }
    // c1 (3) and c2 (9) from a   (t<12)
    if (t<12){
      float cv[4]={0.f,0.f,0.f,0.f};
      for (int k=0;k<32;k+=4){
        const float w0=WcS[k*12+t], w1=WcS[(k+1)*12+t], w2=WcS[(k+2)*12+t], w3=WcS[(k+3)*12+t];
        #pragma unroll
        for (int jc=0;jc<4;jc++){
          const float4 avv = *(const float4*)&aS[(r*4+jc)*32+k];
          cv[jc] += avv.x*w0+avv.y*w1+avv.z*w2+avv.w*w3;
        }
      }
      #pragma unroll
      for (int jc=0;jc<4;jc++) cS[(r*4+jc)*12+t]=cv[jc];
    }
    // offset accumulation: v_msg[o][x] = c1[o]*dhat[x] + sum_c c2[o][c]*l1[j][c][x]   (t<9)
    if (t<9){
      const int o=t/3, x=t-o*3;
      #pragma unroll
      for (int jc=0;jc<4;jc++){
        if (!vals[jc]) continue;
        const int jb=(b<<8)+jjs[jc];
        const float comp = (x==0)?jxs[jc]:((x==1)?jys[jc]:jzs[jc]);
        const float dh = comp/(dsts[jc]+1e-8f);
        const float* cr = &cS[(r*4+jc)*12];
        float val = cr[o]*dh;
        const float caxj = xyz[(jb*3+1)*3+x];
        #pragma unroll
        for (int c=0;c<3;c++){
          val += cr[3+o*3+c]*(xyz[(jb*3+c)*3+x]-caxj);
        }
        ofA += val;
      }
    }
  }

  if (t<16) redS[r][t]=stA;
  if (t<9)  redO[r][t]=ofA;
  __syncthreads();
  const float invd = 1.f/fmaxf((float)n,1.f);
  if (tid<16){
    float s=0.f;
    for (int r2=0;r2<8;r2++) s+=redS[r2][tid];
    out[4608 + bid*16 + tid] = s*invd;     // state
  }
  if (tid<9){
    float s=0.f;
    for (int r2=0;r2<8;r2++) s+=redO[r2][tid];
    offF[tid]=s*invd;
  }
  __syncthreads();
  if (tid<9){
    const int o=tid/3, x=tid-o*3;
    const float cac = (x==0)?cax:((x==1)?cay:caz);
    const float CA = cac + offF[3+x];      // offset[:,:,1]
    const float v = (o==1)? CA : (CA + offF[o*3+x]);
    out[bid*9 + o*3 + x] = v;              // xyz_new
  }
}

extern "C" void kernel_launch(void* const* d_in, const int* in_sizes, int n_in,
                              void* d_out, int out_size, void* d_ws, size_t ws_size,
                              hipStream_t stream)
{
  const float* msa     = (const float*)d_in[0];
  const float* pair    = (const float*)d_in[1];
  const float* xyz     = (const float*)d_in[2];
  const float* seq1hot = (const float*)d_in[3];
  const float* g_msa   = (const float*)d_in[4];
  const float* b_msa   = (const float*)d_in[5];
  const float* g_pair  = (const float*)d_in[6];
  const float* b_pair  = (const float*)d_in[7];
  const float* Wq      = (const float*)d_in[8];
  const float* bq      = (const float*)d_in[9];
  const float* Wk      = (const float*)d_in[10];
  const float* bk      = (const float*)d_in[11];
  const float* Wx      = (const float*)d_in[12];
  const float* bx      = (const float*)d_in[13];
  const float* g_node  = (const float*)d_in[14];
  const float* b_node  = (const float*)d_in[15];
  const float* We      = (const float*)d_in[16];
  const float* be      = (const float*)d_in[17];
  const float* g_edge  = (const float*)d_in[18];
  const float* b_edge  = (const float*)d_in[19];
  const float* Wa      = (const float*)d_in[20];
  const float* ba      = (const float*)d_in[21];
  const float* W0      = (const float*)d_in[22];
  const float* b0      = (const float*)d_in[23];
  const float* Wc1     = (const float*)d_in[24];
  const float* Wc2     = (const float*)d_in[25];
  const int*   idx     = (const int*)d_in[26];
  const int*   topk    = (const int*)d_in[27];
  float* out = (float*)d_out;

  float* node = (float*)d_ws;                   // 16384 f32
  int* cnt    = (int*)((char*)d_ws + 16384*4);  // 512 i32
  int* jlist  = cnt + 512;                      // 131072 i32

  k_node<<<512, 64, 0, stream>>>(msa, seq1hot, g_msa, b_msa, Wq, bq, Wk, bk,
                                 Wx, bx, g_node, b_node, node);
  k_mask<<<512, 256, 0, stream>>>(xyz, idx, topk, cnt, jlist);
  k_main<<<512, 256, 0, stream>>>(pair, xyz, g_pair, b_pair, We, be, g_edge, b_edge,
                                  Wa, ba, W0, b0, Wc1, Wc2, node, cnt, jlist, out);
}